// Round 5
// baseline (45.998 us; speedup 1.0000x reference)
//
#include <hip/hip_runtime.h>
#include <math.h>

// Problem constants (match reference setup_inputs)
#define KF   11
#define PAD  5          // KF/2
#define NB   4
#define CH   3
#define HH   256
#define WW   256
#define HWSZ (HH * WW)
#define EPS2 (1e-3f * 1e-3f)

#define RPB   2                    // output rows per block
#define SROWS (RPB + KF - 1)       // 12 staged rows per channel
#define LW    272                  // LDS row width (floats)
#define LPAD  8                    // left pad: float4 staging stays 16B-aligned
#define LW4   (LW / 4)             // 68 float4 per LDS row
#define STOT  (CH * SROWS * LW4)   // 2448 float4 staging elements

#define GRID  (NB * (HH / RPB))    // 512 blocks
#define FXSCALE 1048576.0f         // 2^20 fixed-point scale for the loss sum

// Fused kernel: reconstruction + Charbonnier + full reduction.
// Per-block sums go into one device-scope fixed-point atomic (bit-exact,
// order-independent); an acq_rel counter elects the last block, which
// converts the integer total to the float mean and writes d_out.
// ws layout: [0..7] u64 fixed-point total, [8..11] u32 block counter
// (both zeroed each call by a 16 B hipMemsetAsync node).
__global__ __launch_bounds__(256, 2) void recon_charbonnier_fused(
    const float* __restrict__ image1,
    const float* __restrict__ image2,
    const float* __restrict__ filters,
    unsigned long long* __restrict__ total_fx,
    unsigned int* __restrict__ counter,
    float* __restrict__ out)
{
    __shared__ float limg[CH][SROWS][LW];   // 39,168 B
    __shared__ float part[CH][RPB][WW];     //  6,144 B
    __shared__ float wsum[4];

    const int tid  = threadIdx.x;
    const int p    = tid & 63;
    const int r    = (tid >> 6) & 1;
    const int half = tid >> 7;
    const int b    = blockIdx.x;
    const int n    = b >> 7;            // 4 batches
    const int h0   = (b & 127) << 1;    // 128 bands of 2 rows

    const float* __restrict__ img1n = image1 + (size_t)n * CH * HWSZ;

    // ---- stage image1 band (rows h0-5 .. h0+6, 3 ch) into LDS, zero halo ----
    for (int idx = tid; idx < STOT; idx += 256) {
        const int row = idx / LW4;            // ch*SROWS + rr
        const int c4  = idx - row * LW4;      // 0..67
        const int ch  = row / SROWS;
        const int rr  = row - ch * SROWS;
        const int grow = h0 + rr - PAD;
        const int gcol = (c4 << 2) - LPAD;
        float4 v = make_float4(0.f, 0.f, 0.f, 0.f);
        if ((unsigned)grow < (unsigned)HH && (unsigned)gcol <= (unsigned)(WW - 4))
            v = *(const float4*)(img1n + (size_t)ch * HWSZ
                                       + (size_t)grow * WW + gcol);
        *(float4*)&limg[ch][rr][c4 << 2] = v;
    }
    __syncthreads();

    // ---- tap loop over this thread's dh range, prefetch-pipelined ----
    const int w0 = p << 2;
    const float* __restrict__ fp = filters + (size_t)n * (KF * KF) * HWSZ
                                           + (size_t)(h0 + r) * WW + w0;

    const int dhBeg = half ? 6 : 0;       // wave-uniform
    const int dhCnt = half ? 5 : 6;

    float acc[CH][4] = {};
    float4 fv[KF], fvn[KF];

    #pragma unroll
    for (int dw = 0; dw < KF; ++dw)
        fv[dw] = *(const float4*)(fp + (size_t)(dhBeg * KF + dw) * HWSZ);

    for (int i = 0; i < dhCnt; ++i) {
        const int dh = dhBeg + i;
        if (i + 1 < dhCnt) {              // prefetch next tap-row's filters
            #pragma unroll
            for (int dw = 0; dw < KF; ++dw)
                fvn[dw] = *(const float4*)(fp + (size_t)((dh + 1) * KF + dw) * HWSZ);
        }

        #pragma unroll
        for (int ch = 0; ch < CH; ++ch) {
            // win[j] = image1[ch][h0+r+dh-5][w0 + j - 5]  (zero-padded)
            const float* __restrict__ lrow = &limg[ch][r + dh][w0 + 3];
            float win[16];
            #pragma unroll
            for (int j = 0; j < 16; ++j) win[j] = lrow[j];

            #pragma unroll
            for (int dw = 0; dw < KF; ++dw) {
                acc[ch][0] = fmaf(fv[dw].x, win[dw + 0], acc[ch][0]);
                acc[ch][1] = fmaf(fv[dw].y, win[dw + 1], acc[ch][1]);
                acc[ch][2] = fmaf(fv[dw].z, win[dw + 2], acc[ch][2]);
                acc[ch][3] = fmaf(fv[dw].w, win[dw + 3], acc[ch][3]);
            }
        }

        #pragma unroll
        for (int dw = 0; dw < KF; ++dw) fv[dw] = fvn[dw];
    }

    // ---- combine tap halves via LDS ----
    if (half) {
        #pragma unroll
        for (int ch = 0; ch < CH; ++ch)
            *(float4*)&part[ch][r][w0] =
                make_float4(acc[ch][0], acc[ch][1], acc[ch][2], acc[ch][3]);
    }
    __syncthreads();

    float s = 0.f;
    if (!half) {
        const float* __restrict__ img2p = image2 + (size_t)n * CH * HWSZ
                                                 + (size_t)(h0 + r) * WW + w0;
        #pragma unroll
        for (int ch = 0; ch < CH; ++ch) {
            const float4 pr = *(const float4*)&part[ch][r][w0];
            const float4 t2 = *(const float4*)(img2p + (size_t)ch * HWSZ);
            const float d0 = acc[ch][0] + pr.x - t2.x;
            const float d1 = acc[ch][1] + pr.y - t2.y;
            const float d2 = acc[ch][2] + pr.z - t2.z;
            const float d3 = acc[ch][3] + pr.w - t2.w;
            s += sqrtf(d0 * d0 + EPS2) + sqrtf(d1 * d1 + EPS2)
               + sqrtf(d2 * d2 + EPS2) + sqrtf(d3 * d3 + EPS2);
        }
    }

    // ---- block reduction (4 waves of 64; half1 waves contribute 0) ----
    #pragma unroll
    for (int off = 32; off > 0; off >>= 1)
        s += __shfl_down(s, off, 64);
    if ((tid & 63) == 0) wsum[tid >> 6] = s;
    __syncthreads();

    // ---- fused global reduction: fixed-point atomic + last-block-done ----
    if (tid == 0) {
        const float bsum = (wsum[0] + wsum[1]) + (wsum[2] + wsum[3]);
        const unsigned long long q =
            (unsigned long long)llrintf(bsum * FXSCALE);
        __hip_atomic_fetch_add(total_fx, q,
                               __ATOMIC_RELAXED, __HIP_MEMORY_SCOPE_AGENT);
        const unsigned int old =
            __hip_atomic_fetch_add(counter, 1u,
                                   __ATOMIC_ACQ_REL, __HIP_MEMORY_SCOPE_AGENT);
        if (old == GRID - 1) {            // last block: finalize
            const unsigned long long t =
                __hip_atomic_load(total_fx,
                                  __ATOMIC_ACQUIRE, __HIP_MEMORY_SCOPE_AGENT);
            out[0] = (float)((double)t /
                             ((double)FXSCALE * (double)(NB * CH * HH * WW)));
        }
    }
}

extern "C" void kernel_launch(void* const* d_in, const int* in_sizes, int n_in,
                              void* d_out, int out_size, void* d_ws, size_t ws_size,
                              hipStream_t stream) {
    const float* image1  = (const float*)d_in[0];
    const float* image2  = (const float*)d_in[1];
    const float* filters = (const float*)d_in[2];
    float* out = (float*)d_out;

    unsigned long long* total_fx = (unsigned long long*)d_ws;       // 8 B
    unsigned int*       counter  = (unsigned int*)((char*)d_ws + 8); // 4 B

    // zero the accumulator + counter each call (graph-capture-safe)
    hipMemsetAsync(d_ws, 0, 16, stream);

    recon_charbonnier_fused<<<GRID, 256, 0, stream>>>(image1, image2, filters,
                                                      total_fx, counter, out);
}

// Round 6
// 30.736 us; speedup vs baseline: 1.4965x; 1.4965x over previous
//
#include <hip/hip_runtime.h>
#include <math.h>

// Problem constants (match reference setup_inputs)
#define KF   11
#define PAD  5          // KF/2
#define NB   4
#define CH   3
#define HH   256
#define WW   256
#define HWSZ (HH * WW)
#define EPS2 (1e-3f * 1e-3f)

#define RPB   2                    // output rows per block
#define SROWS (RPB + KF - 1)       // 12 staged rows per channel
#define LW    272                  // LDS row width (floats)
#define LPAD  8                    // left pad: quad-aligned windows cover the -5 halo
#define LW4   (LW / 4)             // 68 float4 per LDS row
#define STOT  (CH * SROWS * LW4)   // 2448 float4 staging elements

// One block (256 threads = 4 waves) per (n, 2-row band). Thread layout:
//   p    = tid & 63        -> pixel quad, w = 4p..4p+3
//   r    = (tid >> 6) & 1  -> output row h0 + r
//   half = tid >> 7        -> tap-row half (0: dh 0..5, 1: dh 6..10)
// All LDS window reads are QUAD-ALIGNED b128 (cols 4p..4p+19); the +3 window
// offset is a register index, not an address -> zero bank conflicts
// (round-5 profile showed 2.8M conflict cycles from misaligned b32/b64
// remainder reads at col 4p+3).
__global__ __launch_bounds__(256, 2) void recon_charbonnier_kernel(
    const float* __restrict__ image1,
    const float* __restrict__ image2,
    const float* __restrict__ filters,
    float* __restrict__ block_sums)
{
    __shared__ float limg[CH][SROWS][LW];   // 39,168 B
    __shared__ float part[CH][RPB][WW];     //  6,144 B
    __shared__ float wsum[4];

    const int tid  = threadIdx.x;
    const int p    = tid & 63;
    const int r    = (tid >> 6) & 1;
    const int half = tid >> 7;
    const int b    = blockIdx.x;
    const int n    = b >> 7;            // 4 batches
    const int h0   = (b & 127) << 1;    // 128 bands of 2 rows

    const float* __restrict__ img1n = image1 + (size_t)n * CH * HWSZ;

    // ---- stage image1 band (rows h0-5 .. h0+6, 3 ch) into LDS, zero halo ----
    for (int idx = tid; idx < STOT; idx += 256) {
        const int row = idx / LW4;            // ch*SROWS + rr
        const int c4  = idx - row * LW4;      // 0..67
        const int ch  = row / SROWS;
        const int rr  = row - ch * SROWS;
        const int grow = h0 + rr - PAD;
        const int gcol = (c4 << 2) - LPAD;
        float4 v = make_float4(0.f, 0.f, 0.f, 0.f);
        if ((unsigned)grow < (unsigned)HH && (unsigned)gcol <= (unsigned)(WW - 4))
            v = *(const float4*)(img1n + (size_t)ch * HWSZ
                                       + (size_t)grow * WW + gcol);
        *(float4*)&limg[ch][rr][c4 << 2] = v;
    }
    __syncthreads();

    // ---- tap loop over this thread's dh range ----
    const int w0 = p << 2;
    const float* __restrict__ fp = filters + (size_t)n * (KF * KF) * HWSZ
                                           + (size_t)(h0 + r) * WW + w0;

    const int dhBeg = half ? 6 : 0;       // wave-uniform
    const int dhEnd = half ? KF : 6;

    float acc[CH][4] = {};

    for (int dh = dhBeg; dh < dhEnd; ++dh) {
        float4 fv[KF];
        #pragma unroll
        for (int dw = 0; dw < KF; ++dw)
            fv[dw] = *(const float4*)(fp + (size_t)(dh * KF + dw) * HWSZ);

        #pragma unroll
        for (int ch = 0; ch < CH; ++ch) {
            // quad-aligned window: win[k] = limg[ch][r+dh][4p + k], k=0..19
            // (global col = 4p + k - 8; needed range 4p-5 .. 4p+8 is inside)
            float win[20];
            #pragma unroll
            for (int k = 0; k < 5; ++k) {
                const float4 q = *(const float4*)&limg[ch][r + dh][w0 + (k << 2)];
                win[4 * k + 0] = q.x;
                win[4 * k + 1] = q.y;
                win[4 * k + 2] = q.z;
                win[4 * k + 3] = q.w;
            }
            // output px w0+j needs global col (w0+j) + dw - 5 -> win[dw+j+3]
            #pragma unroll
            for (int dw = 0; dw < KF; ++dw) {
                acc[ch][0] = fmaf(fv[dw].x, win[dw + 3], acc[ch][0]);
                acc[ch][1] = fmaf(fv[dw].y, win[dw + 4], acc[ch][1]);
                acc[ch][2] = fmaf(fv[dw].z, win[dw + 5], acc[ch][2]);
                acc[ch][3] = fmaf(fv[dw].w, win[dw + 6], acc[ch][3]);
            }
        }
    }

    // ---- combine tap halves via LDS ----
    if (half) {
        #pragma unroll
        for (int ch = 0; ch < CH; ++ch)
            *(float4*)&part[ch][r][w0] =
                make_float4(acc[ch][0], acc[ch][1], acc[ch][2], acc[ch][3]);
    }
    __syncthreads();

    float s = 0.f;
    if (!half) {
        const float* __restrict__ img2p = image2 + (size_t)n * CH * HWSZ
                                                 + (size_t)(h0 + r) * WW + w0;
        #pragma unroll
        for (int ch = 0; ch < CH; ++ch) {
            const float4 pr = *(const float4*)&part[ch][r][w0];
            const float4 t2 = *(const float4*)(img2p + (size_t)ch * HWSZ);
            const float d0 = acc[ch][0] + pr.x - t2.x;
            const float d1 = acc[ch][1] + pr.y - t2.y;
            const float d2 = acc[ch][2] + pr.z - t2.z;
            const float d3 = acc[ch][3] + pr.w - t2.w;
            s += sqrtf(d0 * d0 + EPS2) + sqrtf(d1 * d1 + EPS2)
               + sqrtf(d2 * d2 + EPS2) + sqrtf(d3 * d3 + EPS2);
        }
    }

    // ---- block reduction (4 waves of 64; half1 waves contribute 0) ----
    #pragma unroll
    for (int off = 32; off > 0; off >>= 1)
        s += __shfl_down(s, off, 64);
    if ((tid & 63) == 0) wsum[tid >> 6] = s;
    __syncthreads();
    if (tid == 0)
        block_sums[blockIdx.x] = (wsum[0] + wsum[1]) + (wsum[2] + wsum[3]);
}

// Kernel 2: reduce the 512 per-block sums into the scalar mean.
__global__ __launch_bounds__(256) void final_reduce_kernel(
    const float* __restrict__ block_sums,
    float* __restrict__ out)
{
    float s = block_sums[threadIdx.x] + block_sums[threadIdx.x + 256];

    #pragma unroll
    for (int off = 32; off > 0; off >>= 1)
        s += __shfl_down(s, off, 64);

    __shared__ float wsum[4];
    if ((threadIdx.x & 63) == 0) wsum[threadIdx.x >> 6] = s;
    __syncthreads();
    if (threadIdx.x == 0) {
        const float inv_count = 1.0f / (float)(NB * CH * HH * WW);
        out[0] = ((wsum[0] + wsum[1]) + (wsum[2] + wsum[3])) * inv_count;
    }
}

extern "C" void kernel_launch(void* const* d_in, const int* in_sizes, int n_in,
                              void* d_out, int out_size, void* d_ws, size_t ws_size,
                              hipStream_t stream) {
    const float* image1  = (const float*)d_in[0];
    const float* image2  = (const float*)d_in[1];
    const float* filters = (const float*)d_in[2];
    float* out = (float*)d_out;
    float* block_sums = (float*)d_ws;   // 512 floats

    const int grid = NB * (HH / RPB);   // 512 blocks, one per (n, 2-row band)

    recon_charbonnier_kernel<<<grid, 256, 0, stream>>>(image1, image2, filters,
                                                       block_sums);
    final_reduce_kernel<<<1, 256, 0, stream>>>(block_sums, out);
}